// Round 11
// baseline (132.529 us; speedup 1.0000x reference)
//
#include <hip/hip_runtime.h>
#include <math.h>

#define NN 320      // particles
#define DD 64       // dim
#define ROWF (NN * 2)                    // floats per DAH row (da,dh interleaved)
#define NPERM 1001  // identity + 1000 permutations
#define KPB 4       // perms per qf block
#define NPG ((NPERM + KPB - 1) / KPB)    // 251 perm-groups
#define RSPLIT 4                         // row chunks per perm-group
#define RCH (NN / RSPLIT)                // 80 rows per block
#define NSLOT (RCH / 16)                 // 5 slots x 16 rowoffs = 80 rows
#define NW 10                            // u32 words per 320-bit mask
#define NPAIRF ((double)(NN * (NN - 1) / 2))   // 51040

// ---------------------------------------------------------------------------
// Math (u in {+-1} since Fv=-1, Bv=+1; PASSING rounds 1-10, absmax 0):
//   d_ab = da_ab + (u_a*u_b)*dh_ab,  da=(dp+dm)/2, dh=(dp-dm)/2
//   SV_ordered = C0 + u^T Dh u - 2 q^T Da q - 2 (qu)^T Dh (qu), C0 = Sum da
//   SV2 = N*S - |y|^2,  y = Sum_a u_a x_a
// Round-10 post-mortem: stagger NEUTRAL -> L2-contention falsified. All
// theories for the invariant ~38us qf are now dead EXCEPT per-block serial
// sweep length (never varied cleanly: round-2's split was confounded by the
// scattered UQV preamble, round-5's by lb(512,4) spills). THIS ROUND: clean
// 4x row-split. 251x4 = 1004 blocks x 1024 thr (2/CU), each sweeps 80 rows
// (5 slots), bit-decode preamble kept. Partials to ws, tiny final kernel.
// Pre-committed decision rule: dur ~75-82 -> serial chain was the cost;
// dur ~94-99 -> fixed overhead dominates -> declare roofline next round.
// ws: srow@0 | rsda@4096 | part@8192 (1004*16 f64) | ypart@270336
//     (1004*4*64 f32) | DAH@2097152 (800KB)
// ---------------------------------------------------------------------------

// Gram row; DAH = {da,dh}; per-row srow/rsda partials (no atomics).
__global__ __launch_bounds__(NN) void dah_kernel(const float* __restrict__ data,
                                                 float2* __restrict__ DAH,
                                                 double* __restrict__ srow,
                                                 double* __restrict__ rsda) {
    __shared__ float rowa[DD];
    __shared__ double cr[5];
    const int a = blockIdx.x;
    const int t = threadIdx.x;
    if (t < DD) rowa[t] = data[a * DD + t];
    __syncthreads();
    const float* rb = data + t * DD;
    float g = 0.f, sa = 0.f, st = 0.f;
#pragma unroll
    for (int k = 0; k < DD; k += 4) {
        const float4 x = *(const float4*)(rb + k);
        const float r0 = rowa[k], r1 = rowa[k + 1], r2 = rowa[k + 2], r3 = rowa[k + 3];
        g  = fmaf(r0, x.x, g);   g  = fmaf(r1, x.y, g);
        g  = fmaf(r2, x.z, g);   g  = fmaf(r3, x.w, g);
        sa = fmaf(r0, r0, sa);   sa = fmaf(r1, r1, sa);
        sa = fmaf(r2, r2, sa);   sa = fmaf(r3, r3, sa);
        st = fmaf(x.x, x.x, st); st = fmaf(x.y, x.y, st);
        st = fmaf(x.z, x.z, st); st = fmaf(x.w, x.w, st);
    }
    const float sum = sa + st;
    const float dp = sqrtf(fmaxf(fmaf(-2.f, g, sum), 0.f));
    const float dm = sqrtf(fmaxf(fmaf( 2.f, g, sum), 0.f));
    const float da = 0.5f * (dp + dm);
    const float dh = 0.5f * (dp - dm);
    DAH[(size_t)a * NN + t] = make_float2(da, dh);

    double cd = (double)da;
    for (int off = 32; off; off >>= 1) cd += __shfl_down(cd, off, 64);
    const int wid = t >> 6, lane = t & 63;
    if (lane == 0) cr[wid] = cd;
    __syncthreads();
    if (t == 0) {
        double tot = 0.0;
#pragma unroll
        for (int i = 0; i < 5; ++i) tot += cr[i];
        rsda[a] = tot;                 // row-sum of da
        srow[a] = (double)sa;          // |x_a|^2
    }
}

// One 1024-thread block = 4 perms x 80 rows (chunk rc). 64 strips x 16
// rowoffs x 5 slots. Same per-thread pattern as round 9; 1/4 the serial
// chain. Writes 12 f64 A-partials + 4x64 f32 y-partials; no atomics.
__global__ __launch_bounds__(1024) void qf_kernel(const float* __restrict__ data,
                                                  const int* __restrict__ types,
                                                  const int* __restrict__ perms,
                                                  const float* __restrict__ fermp,
                                                  const float* __restrict__ bosp,
                                                  const float* __restrict__ DAHf,
                                                  double* __restrict__ part,
                                                  float* __restrict__ ypart) {
    __shared__ unsigned cb[KPB][2 * NW];
    __shared__ __align__(16) float rcoef[RCH * 20];    // [r][k pad5] {u,q,v,0} 6.4KB
    __shared__ float ysh[KPB][4][DD];
    __shared__ double red[16][12];

    const int pg   = blockIdx.x;
    const int rc   = blockIdx.y;
    const int row0 = rc * RCH;
    const int t    = threadIdx.x;
    const int strip  = t & 63;        // column strip: cols strip + 64e, e=0..4
    const int rowoff = t >> 6;        // 0..15 (= wave id; wave-uniform)

    // ---- issue slot-0 DAH loads immediately (hide under decode) ----
    const float* gp = DAHf + (size_t)(row0 + rowoff) * ROWF + 2 * strip;
    float2 m0 = *(const float2*)(gp);
    float2 m1 = *(const float2*)(gp + 128);
    float2 m2 = *(const float2*)(gp + 256);
    float2 m3 = *(const float2*)(gp + 384);
    float2 m4 = *(const float2*)(gp + 512);

    // ---- inline coefficient decode (bits in LDS) ----
    if (t < KPB * 2 * NW) ((unsigned*)cb)[t] = 0u;
    __syncthreads();
    const float Fv = *fermp, Bv = *bosp;
    if (t < NN) {
        const int i  = t;
        const int ti = types[i];
#pragma unroll
        for (int k = 0; k < KPB; ++k) {
            int p = pg * KPB + k; if (p >= NPERM) p = NPERM - 1;
            const int a  = (p == 0) ? i : perms[(size_t)(p - 1) * NN + i];
            const int ta = types[a];
            float u = 1.f;
            if (a != i) u = (ti == 0 && ta == 0) ? Fv : ((ti == 1 && ta == 1) ? Bv : 1.f);
            if (u < 0.f) atomicOr(&cb[k][a >> 5], 1u << (a & 31));
            if (ti == 0) atomicOr(&cb[k][NW + (a >> 5)], 1u << (a & 31));
        }
    }
    __syncthreads();

    // Row coefficients for this chunk only (80 rows), stride 80 B.
    for (int j = t; j < RCH * KPB; j += 1024) {
        const int r = j >> 2, k = j & 3;
        const int a = row0 + r;
        const unsigned ubit = (cb[k][a >> 5]        >> (a & 31)) & 1u;
        const unsigned qbit = (cb[k][NW + (a >> 5)] >> (a & 31)) & 1u;
        const float u = ubit ? -1.f : 1.f;
        *(float4*)&rcoef[r * 20 + k * 4] =
            make_float4(u, qbit ? 1.f : 0.f, qbit ? u : 0.f, 0.f);
    }

    // Column cache: 5 strided cols x 3 coefs x 4 perms = 60 VGPR.
    float ub[KPB][5], qb[KPB][5], vb[KPB][5];
#pragma unroll
    for (int k = 0; k < KPB; ++k) {
#pragma unroll
        for (int e = 0; e < 5; ++e) {
            const int w = (strip >> 5) + 2 * e, b = strip & 31;
            const float u = ((cb[k][w] >> b) & 1u) ? -1.f : 1.f;
            const bool  q = ((cb[k][NW + w] >> b) & 1u) != 0u;
            ub[k][e] = u;
            qb[k][e] = q ? 1.f : 0.f;
            vb[k][e] = q ? u : 0.f;
        }
    }
    __syncthreads();

    // ---- main sweep: 5 slots x 16 rowoffs = 80 rows ----
    float A2[KPB] = {0.f, 0.f, 0.f, 0.f};   // u^T Dh u
    float A3[KPB] = {0.f, 0.f, 0.f, 0.f};   // q^T Da q
    float A4[KPB] = {0.f, 0.f, 0.f, 0.f};   // (qu)^T Dh (qu)

    auto row_compute = [&](const float* ap) {
#pragma unroll
        for (int k = 0; k < KPB; ++k) {
            const float4 rp = *(const float4*)(ap + 4 * k);  // {u_a, q_a, v_a}
            float r2 = ub[k][0] * m0.y;
            float r3 = qb[k][0] * m0.x;
            float r4 = vb[k][0] * m0.y;
            r2 = fmaf(ub[k][1], m1.y, r2); r3 = fmaf(qb[k][1], m1.x, r3); r4 = fmaf(vb[k][1], m1.y, r4);
            r2 = fmaf(ub[k][2], m2.y, r2); r3 = fmaf(qb[k][2], m2.x, r3); r4 = fmaf(vb[k][2], m2.y, r4);
            r2 = fmaf(ub[k][3], m3.y, r2); r3 = fmaf(qb[k][3], m3.x, r3); r4 = fmaf(vb[k][3], m3.y, r4);
            r2 = fmaf(ub[k][4], m4.y, r2); r3 = fmaf(qb[k][4], m4.x, r3); r4 = fmaf(vb[k][4], m4.y, r4);
            A2[k] = fmaf(rp.x, r2, A2[k]);
            A3[k] = fmaf(rp.y, r3, A3[k]);
            A4[k] = fmaf(rp.z, r4, A4[k]);
        }
    };

    for (int slot = 0; slot < NSLOT; ++slot) {
        const float* gq = (slot < NSLOT - 1) ? (gp + 16 * ROWF) : gp;
        const float2 n0 = *(const float2*)(gq);
        const float2 n1 = *(const float2*)(gq + 128);
        const float2 n2 = *(const float2*)(gq + 256);
        const float2 n3 = *(const float2*)(gq + 384);
        const float2 n4 = *(const float2*)(gq + 512);
        row_compute(rcoef + (slot * 16 + rowoff) * 20);
        m0 = n0; m1 = n1; m2 = n2; m3 = n3; m4 = n4;
        gp = gq;
    }

    // ---- y partials over this chunk: 4 perms x 4 groups x 64 dims ----
    {
        const int k = t >> 8, sub = t & 255;
        const int j = sub >> 6, d = sub & 63;
        float acc = 0.f;
        for (int r = j * 20; r < j * 20 + 20; ++r)
            acc = fmaf(rcoef[r * 20 + k * 4], data[(size_t)(row0 + r) * DD + d], acc);
        ysh[k][j][d] = acc;
    }
    __syncthreads();
    if (t < KPB * DD) {
        const int k = t / DD, d = t % DD;
        const float yp = (ysh[k][0][d] + ysh[k][1][d]) + (ysh[k][2][d] + ysh[k][3][d]);
        ypart[(((size_t)pg * RSPLIT + rc) * KPB + k) * DD + d] = yp;
    }

    // ---- A partials: f32 -> f64 -> wave -> cross-wave -> ws ----
    double rd[12];
#pragma unroll
    for (int k = 0; k < KPB; ++k) {
        rd[k]     = (double)A2[k];
        rd[4 + k] = (double)A3[k];
        rd[8 + k] = (double)A4[k];
    }
    for (int off = 32; off; off >>= 1) {
#pragma unroll
        for (int j = 0; j < 12; ++j) rd[j] += __shfl_down(rd[j], off, 64);
    }
    const int wid = t >> 6, lane = t & 63;
    if (lane == 0) {
#pragma unroll
        for (int j = 0; j < 12; ++j) red[wid][j] = rd[j];
    }
    __syncthreads();
    if (t == 0) {
        double* dst = part + ((size_t)pg * RSPLIT + rc) * 16;
#pragma unroll
        for (int j = 0; j < 12; ++j) {
            double v = 0.0;
            for (int w = 0; w < 16; ++w) v += red[w][j];
            dst[j] = v;
        }
    }
}

// 251 blocks x 256 thr. Wave k handles perm pg*4+k: |y|^2 from ypart chunks,
// T2..T4 from part chunks; wave 0 reduces S/C0 from srow/rsda.
__global__ __launch_bounds__(256) void final_kernel(const double* __restrict__ srow,
                                                    const double* __restrict__ rsda,
                                                    const double* __restrict__ part,
                                                    const float* __restrict__ ypart,
                                                    float* __restrict__ out) {
    __shared__ double sSh, sCh;
    const int pg = blockIdx.x;
    const int t  = threadIdx.x;
    const int wid = t >> 6, lane = t & 63;

    if (wid == 0) {                       // S and C0 (320-wide f64 reduce)
        double sS = 0.0, sC = 0.0;
#pragma unroll
        for (int i = 0; i < 5; ++i) { sS += srow[lane + 64 * i]; sC += rsda[lane + 64 * i]; }
        for (int off = 32; off; off >>= 1) {
            sS += __shfl_down(sS, off, 64);
            sC += __shfl_down(sC, off, 64);
        }
        if (lane == 0) { sSh = sS; sCh = sC; }
    }
    __syncthreads();

    // |y|^2 for perm wid: sum chunk partials per dim, square, reduce.
    float yv = 0.f;
#pragma unroll
    for (int rc = 0; rc < RSPLIT; ++rc)
        yv += ypart[(((size_t)pg * RSPLIT + rc) * KPB + wid) * DD + lane];
    double yy = (double)yv * (double)yv;
    for (int off = 32; off; off >>= 1) yy += __shfl_down(yy, off, 64);

    if (lane == 0) {
        const int p = pg * KPB + wid;
        if (p < NPERM) {
            const double S = sSh, C0 = sCh;
            double T2 = 0.0, T3 = 0.0, T4 = 0.0;
#pragma unroll
            for (int rc = 0; rc < RSPLIT; ++rc) {
                const double* pb = part + ((size_t)pg * RSPLIT + rc) * 16;
                T2 += pb[wid];
                T3 += pb[4 + wid];
                T4 += pb[8 + wid];
            }
            const double SV  = 0.5 * (C0 + T2 - 2.0 * T3 - 2.0 * T4);
            const double SV2 = (double)NN * S - yy;
            out[p] = (float)((SV2 - SV * SV / NPAIRF) / (NPAIRF - 1.0));
        }
    }
}

extern "C" void kernel_launch(void* const* d_in, const int* in_sizes, int n_in,
                              void* d_out, int out_size, void* d_ws, size_t ws_size,
                              hipStream_t stream) {
    const float* data  = (const float*)d_in[0];
    const float* fermp = (const float*)d_in[1];
    const float* bosp  = (const float*)d_in[2];
    const int*   types = (const int*)d_in[3];
    const int*   perms = (const int*)d_in[4];
    float* out = (float*)d_out;

    double* srow  = (double*)d_ws;                      // 320 f64
    double* rsda  = (double*)((char*)d_ws + 4096);      // 320 f64
    double* part  = (double*)((char*)d_ws + 8192);      // 1004*16 f64 = 128.5 KB
    float*  ypart = (float*)((char*)d_ws + 270336);     // 1004*4*64 f32 = 1.03 MB
    float2* DAH   = (float2*)((char*)d_ws + 2097152);   // 320*320 float2 = 800 KB

    dah_kernel<<<NN, NN, 0, stream>>>(data, DAH, srow, rsda);
    qf_kernel<<<dim3(NPG, RSPLIT), 1024, 0, stream>>>(data, types, perms, fermp, bosp,
                                                      (const float*)DAH, part, ypart);
    final_kernel<<<NPG, 256, 0, stream>>>(srow, rsda, part, ypart, out);
}